// Round 3
// baseline (287.676 us; speedup 1.0000x reference)
//
#include <hip/hip_runtime.h>

typedef __bf16 bf16;
typedef __attribute__((ext_vector_type(8))) __bf16 bf16x8;
typedef __attribute__((ext_vector_type(4))) float f32x4;

#define MFMA_16x16x32(a, b, c) __builtin_amdgcn_mfma_f32_16x16x32_bf16((a), (b), (c), 0, 0, 0)

#define NEG_BIG (-1e30f)

__device__ __forceinline__ void gload_lds16(void* lds, const void* g) {
  __builtin_amdgcn_global_load_lds(
      (const __attribute__((address_space(1))) void*)g,
      (__attribute__((address_space(3))) void*)lds, 16, 0, 0);
}

// ---------------------------------------------------------------------------
// f32 -> bf16 conversion (vectorized: 8 el / thread). n8 = n/8.
// ---------------------------------------------------------------------------
__global__ void f32_to_bf16(const float* __restrict__ src, bf16* __restrict__ dst,
                            int n8) {
  const int i = blockIdx.x * blockDim.x + threadIdx.x;
  if (i >= n8) return;
  const float4 a = ((const float4*)src)[i * 2 + 0];
  const float4 b = ((const float4*)src)[i * 2 + 1];
  bf16x8 o;
  o[0] = (bf16)a.x; o[1] = (bf16)a.y; o[2] = (bf16)a.z; o[3] = (bf16)a.w;
  o[4] = (bf16)b.x; o[5] = (bf16)b.y; o[6] = (bf16)b.z; o[7] = (bf16)b.w;
  ((bf16x8*)dst)[i] = o;
}

// ---------------------------------------------------------------------------
// GEMM (BT): out = A[M,K] . W[N,K]^T + bias[N]   (m97 template)
// A, W bf16; bias f32 (direct from d_in).
// OUT_MODE 0: bf16 out, head layout ((b*16+h)*2048+t)*64+d  (Q/K/V)
// OUT_MODE 1: f32 out, plain row-major [M,N]  (final projection -> d_out)
// ---------------------------------------------------------------------------
template <int OUT_MODE, typename OutT>
__global__ void gemm_bt(const bf16* __restrict__ A, const bf16* __restrict__ W,
                        const float* __restrict__ bias, OutT* __restrict__ out,
                        int M, int N, int K) {
  __shared__ __align__(16) bf16 As[128 * 32];
  __shared__ __align__(16) bf16 Bs[128 * 32];
  const int tid = threadIdx.x;
  const int wv = tid >> 6, lane = tid & 63;
  const int wr = wv >> 1, wc = wv & 1;
  const int lr = lane & 15, lg = lane >> 4;
  const int m0 = blockIdx.y * 128, n0 = blockIdx.x * 128;

  f32x4 acc[4][4] = {};

  for (int k0 = 0; k0 < K; k0 += 32) {
    __syncthreads();
#pragma unroll
    for (int j = 0; j < 2; ++j) {
      const int e8 = (j * 256 + tid) * 8;
      const int row = e8 >> 5, col = e8 & 31;
      gload_lds16(As + (size_t)(j * 256 + wv * 64) * 8,
                  A + (size_t)(m0 + row) * K + k0 + col);
      gload_lds16(Bs + (size_t)(j * 256 + wv * 64) * 8,
                  W + (size_t)(n0 + row) * K + k0 + col);
    }
    __syncthreads();
    bf16x8 af[4], bfr[4];
#pragma unroll
    for (int i = 0; i < 4; ++i)
      af[i] = *(const bf16x8*)&As[(wr * 64 + i * 16 + lr) * 32 + lg * 8];
#pragma unroll
    for (int j = 0; j < 4; ++j)
      bfr[j] = *(const bf16x8*)&Bs[(wc * 64 + j * 16 + lr) * 32 + lg * 8];
#pragma unroll
    for (int i = 0; i < 4; ++i)
#pragma unroll
      for (int j = 0; j < 4; ++j)
        acc[i][j] = MFMA_16x16x32(af[i], bfr[j], acc[i][j]);
  }

#pragma unroll
  for (int j = 0; j < 4; ++j) {
    const int n = n0 + wc * 64 + j * 16 + lr;
    const float bv = bias[n];
#pragma unroll
    for (int i = 0; i < 4; ++i) {
#pragma unroll
      for (int r = 0; r < 4; ++r) {
        const int m = m0 + wr * 64 + i * 16 + lg * 4 + r;
        const float v = acc[i][j][r] + bv;
        if (OUT_MODE == 0) {
          const int b = m >> 11, t = m & 2047, h = n >> 6, d = n & 63;
          out[((size_t)(b * 16 + h) * 2048 + t) * 64 + d] = (OutT)v;
        } else {
          out[(size_t)m * N + n] = (OutT)v;
        }
      }
    }
  }
}

// ---------------------------------------------------------------------------
// Causal flash attention — correctness-first baseline.
// Q,K,V in [B*H, T=2048, D=64] bf16. Output att_out in [B,T,C] bf16.
// Block: 256 thr = 4 waves; 64 q-rows per block, wave w owns rows
// [q0+16w, +16). KV tiles of 64, kv0 <= q0 (causal).
// K fragments direct from global (L2-resident), V transposed into padded
// LDS [64][72], P via padded per-wave LDS [16][72]. Mask = -1e30.
// ---------------------------------------------------------------------------
__global__ void attn_fwd(const bf16* __restrict__ Q, const bf16* __restrict__ Kk,
                         const bf16* __restrict__ V, bf16* __restrict__ attout) {
  __shared__ __align__(16) bf16 Vs[64][72];      // V^T tile: Vs[d][kv]
  __shared__ __align__(16) bf16 Ps[4][16][72];   // per-wave P [q][kv]

  const int tid = threadIdx.x;
  const int wv = tid >> 6, lane = tid & 63;
  const int lr = lane & 15, lg = lane >> 4;
  const int q0 = blockIdx.x * 64, bh = blockIdx.y;
  const size_t bhT = (size_t)bh * 2048;

  const int qrow = q0 + wv * 16 + lr;
  bf16x8 qf[2];
  qf[0] = *(const bf16x8*)(Q + (bhT + qrow) * 64 + lg * 8);
  qf[1] = *(const bf16x8*)(Q + (bhT + qrow) * 64 + 32 + lg * 8);

  f32x4 o[4] = {};
  float m_run[4] = {NEG_BIG, NEG_BIG, NEG_BIG, NEG_BIG};
  float l_run[4] = {0.f, 0.f, 0.f, 0.f};

  for (int kv0 = 0; kv0 <= q0; kv0 += 64) {
    __syncthreads();
    // ---- stage V transposed (plain writes, padded stride) ----
#pragma unroll
    for (int r2 = 0; r2 < 2; ++r2) {
      const int e = (r2 * 256 + tid) * 8;
      const int row = e >> 6, col = e & 63;  // row=kv, col=d base
      const uint4 t4 = *(const uint4*)(V + (bhT + kv0 + row) * 64 + col);
      const bf16* pv = (const bf16*)&t4;
#pragma unroll
      for (int ii = 0; ii < 8; ++ii) Vs[col + ii][row] = pv[ii];
    }
    __syncthreads();

    // ---- S = Q . K^T, K fragments direct from global ----
    f32x4 s[4] = {};
#pragma unroll
    for (int j = 0; j < 4; ++j) {
      const int n = j * 16 + lr;  // kv row
      const bf16x8 kf0 = *(const bf16x8*)(Kk + (bhT + kv0 + n) * 64 + lg * 8);
      s[j] = MFMA_16x16x32(qf[0], kf0, s[j]);
      const bf16x8 kf1 = *(const bf16x8*)(Kk + (bhT + kv0 + n) * 64 + 32 + lg * 8);
      s[j] = MFMA_16x16x32(qf[1], kf1, s[j]);
    }
#pragma unroll
    for (int j = 0; j < 4; ++j) s[j] *= 0.125f;  // 1/sqrt(64)

    if (kv0 == q0) {  // diagonal tile: causal mask
#pragma unroll
      for (int j = 0; j < 4; ++j) {
        const int colk = kv0 + j * 16 + lr;
#pragma unroll
        for (int r = 0; r < 4; ++r) {
          const int rowq = q0 + wv * 16 + lg * 4 + r;
          if (colk > rowq) s[j][r] = NEG_BIG;
        }
      }
    }

    // ---- online softmax: 4 q-rows/lane (r); cols over 16 lanes x 4 j ----
#pragma unroll
    for (int r = 0; r < 4; ++r) {
      float mx = fmaxf(fmaxf(s[0][r], s[1][r]), fmaxf(s[2][r], s[3][r]));
      mx = fmaxf(mx, __shfl_xor(mx, 1));
      mx = fmaxf(mx, __shfl_xor(mx, 2));
      mx = fmaxf(mx, __shfl_xor(mx, 4));
      mx = fmaxf(mx, __shfl_xor(mx, 8));
      const float mnew = fmaxf(m_run[r], mx);
      const float fac = __expf(m_run[r] - mnew);  // 0 on first tile
      float rs = 0.f;
#pragma unroll
      for (int j = 0; j < 4; ++j) {
        const float p = __expf(s[j][r] - mnew);
        s[j][r] = p;
        rs += p;
      }
      rs += __shfl_xor(rs, 1);
      rs += __shfl_xor(rs, 2);
      rs += __shfl_xor(rs, 4);
      rs += __shfl_xor(rs, 8);
      l_run[r] = l_run[r] * fac + rs;
      m_run[r] = mnew;
#pragma unroll
      for (int jd = 0; jd < 4; ++jd) o[jd][r] *= fac;
    }

    // ---- P -> per-wave padded LDS (D-layout write, A-layout read) ----
#pragma unroll
    for (int j = 0; j < 4; ++j)
#pragma unroll
      for (int r = 0; r < 4; ++r)
        Ps[wv][lg * 4 + r][j * 16 + lr] = (bf16)s[j][r];
    const bf16x8 pf0 = *(const bf16x8*)&Ps[wv][lr][lg * 8];
    const bf16x8 pf1 = *(const bf16x8*)&Ps[wv][lr][32 + lg * 8];

    // ---- PV: o[q][d] += P[q][kv] * V[kv][d], B-operand from Vs[d][kv] ----
#pragma unroll
    for (int jd = 0; jd < 4; ++jd) {
      const int n = jd * 16 + lr;  // d
      const bf16x8 vf0 = *(const bf16x8*)&Vs[n][lg * 8];
      o[jd] = MFMA_16x16x32(pf0, vf0, o[jd]);
      const bf16x8 vf1 = *(const bf16x8*)&Vs[n][32 + lg * 8];
      o[jd] = MFMA_16x16x32(pf1, vf1, o[jd]);
    }
  }

  // ---- normalize + store att_out in [B,T,C] ----
  const int b = bh >> 4, h = bh & 15;
#pragma unroll
  for (int jd = 0; jd < 4; ++jd)
#pragma unroll
    for (int r = 0; r < 4; ++r) {
      const int rowq = q0 + wv * 16 + lg * 4 + r;
      const float ov = o[jd][r] / l_run[r];
      attout[((size_t)b * 2048 + rowq) * 1024 + h * 64 + jd * 16 + lr] = (bf16)ov;
    }
}

// ---------------------------------------------------------------------------
extern "C" void kernel_launch(void* const* d_in, const int* in_sizes, int n_in,
                              void* d_out, int out_size, void* d_ws, size_t ws_size,
                              hipStream_t stream) {
  // Inputs are FLOAT32 (reference dtype). Biases used directly as f32.
  const float* x   = (const float*)d_in[0];
  const float* xq  = (const float*)d_in[1];
  const float* Wq  = (const float*)d_in[2];
  const float* bq  = (const float*)d_in[3];
  const float* Wk  = (const float*)d_in[4];
  const float* bk  = (const float*)d_in[5];
  const float* Wv  = (const float*)d_in[6];
  const float* bv  = (const float*)d_in[7];
  const float* Wp  = (const float*)d_in[8];
  const float* bp  = (const float*)d_in[9];
  float* out = (float*)d_out;

  const size_t NTC = 4194304;  // B*T*C = 2*2048*1024
  const size_t NW  = 1048576;  // C*C
  bf16* ws = (bf16*)d_ws;
  bf16* XQb = ws;                    // [B*T, C]
  bf16* Xb  = XQb + NTC;             // [B*T, C]
  bf16* Wqb = Xb + NTC;
  bf16* Wkb = Wqb + NW;
  bf16* Wvb = Wkb + NW;
  bf16* Wpb = Wvb + NW;
  bf16* Qw  = Wpb + NW;              // [B*H, T, D]
  bf16* Kw  = Qw + NTC;
  bf16* Vw  = Kw + NTC;
  bf16* Aw  = Vw + NTC;              // [B, T, C]

  dim3 blk(256);
  // f32 -> bf16 conversions
  f32_to_bf16<<<dim3((NTC / 8 + 255) / 256), blk, 0, stream>>>(xq, XQb, NTC / 8);
  f32_to_bf16<<<dim3((NTC / 8 + 255) / 256), blk, 0, stream>>>(x, Xb, NTC / 8);
  f32_to_bf16<<<dim3((NW / 8 + 255) / 256), blk, 0, stream>>>(Wq, Wqb, NW / 8);
  f32_to_bf16<<<dim3((NW / 8 + 255) / 256), blk, 0, stream>>>(Wk, Wkb, NW / 8);
  f32_to_bf16<<<dim3((NW / 8 + 255) / 256), blk, 0, stream>>>(Wv, Wvb, NW / 8);
  f32_to_bf16<<<dim3((NW / 8 + 255) / 256), blk, 0, stream>>>(Wp, Wpb, NW / 8);

  gemm_bt<0, bf16><<<dim3(8, 32), blk, 0, stream>>>(XQb, Wqb, bq, Qw, 4096, 1024, 1024);
  gemm_bt<0, bf16><<<dim3(8, 32), blk, 0, stream>>>(Xb,  Wkb, bk, Kw, 4096, 1024, 1024);
  gemm_bt<0, bf16><<<dim3(8, 32), blk, 0, stream>>>(Xb,  Wvb, bv, Vw, 4096, 1024, 1024);
  attn_fwd<<<dim3(32, 32), blk, 0, stream>>>(Qw, Kw, Vw, Aw);
  gemm_bt<1, float><<<dim3(8, 32), blk, 0, stream>>>(Aw, Wpb, bp, out, 4096, 1024, 1024);
}